// Round 3
// baseline (339.536 us; speedup 1.0000x reference)
//
#include <hip/hip_runtime.h>

#define N_ATOMS 8192
#define DIM 64
#define N_MOL 256
#define N_LAYERS 3
#define KS 16
#define KCH (N_ATOMS / KS)   // 512 k per split

typedef __attribute__((ext_vector_type(8))) short short8v;
typedef __attribute__((ext_vector_type(4))) float f32x4;
typedef unsigned short ushort_t;

// f32 -> bf16 RTNE (inputs finite)
__device__ __forceinline__ ushort_t f2bf(float x) {
    unsigned u = __float_as_uint(x);
    u += 0x7fffu + ((u >> 16) & 1u);
    return (ushort_t)(u >> 16);
}

// ---------------- embed: v[n][d] = table[fp[n]][d] ----------------
__global__ void embed_kernel(const int* __restrict__ fp,
                             const float* __restrict__ table,
                             float* __restrict__ v) {
    int n = blockIdx.x;
    int d = threadIdx.x;
    v[n * DIM + d] = table[fp[n] * DIM + d];
}

// ---- linear+relu over 64 atoms/block; writes vnext = h (f32, residual init)
// ---- and hT (bf16, [DIM][N_ATOMS]) as the MFMA B-operand ----
__global__ __launch_bounds__(256) void linear_relu_T_kernel(
        const float* __restrict__ v, const float* __restrict__ W,
        const float* __restrict__ b, float* __restrict__ vnext,
        ushort_t* __restrict__ hT) {
    __shared__ float Ws[DIM][DIM + 1];
    __shared__ float vsT[DIM][68];

    const int t = threadIdx.x;
    const int n0 = blockIdx.x * 64;
    for (int i = t; i < DIM * DIM; i += 256) {
        Ws[i >> 6][i & 63] = W[i];
        float val = v[n0 * DIM + i];          // n = n0 + (i>>6), d = i&63
        vsT[i & 63][i >> 6] = val;
    }
    __syncthreads();

    const int e = t & 63;
    const int g = t >> 6;
    float acc[16];
    const float be = b[e];
#pragma unroll
    for (int i = 0; i < 16; ++i) acc[i] = be;

    for (int d = 0; d < DIM; ++d) {
        const float w = Ws[e][d];
        const float4* vp = (const float4*)&vsT[d][g * 16];
        float4 x0 = vp[0], x1 = vp[1], x2 = vp[2], x3 = vp[3];
        acc[0]  += w * x0.x; acc[1]  += w * x0.y; acc[2]  += w * x0.z; acc[3]  += w * x0.w;
        acc[4]  += w * x1.x; acc[5]  += w * x1.y; acc[6]  += w * x1.z; acc[7]  += w * x1.w;
        acc[8]  += w * x2.x; acc[9]  += w * x2.y; acc[10] += w * x2.z; acc[11] += w * x2.w;
        acc[12] += w * x3.x; acc[13] += w * x3.y; acc[14] += w * x3.z; acc[15] += w * x3.w;
    }

    ushort_t hb[16];
#pragma unroll
    for (int i = 0; i < 16; ++i) {
        float hv = acc[i] > 0.f ? acc[i] : 0.f;
        const int n = n0 + g * 16 + i;
        vnext[(size_t)n * DIM + e] = hv;
        hb[i] = f2bf(hv);
    }
    ushort_t* hp = hT + (size_t)e * N_ATOMS + n0 + g * 16;
    *(short8v*)(hp)     = *(short8v*)&hb[0];
    *(short8v*)(hp + 8) = *(short8v*)&hb[8];
}

// ---- pbuf[split] = A[rows, ksplit] @ h[ksplit, :] via MFMA.
// CVT=1: read f32 A, convert in-register, persist bf16 copy to Abf_out.
// CVT=0: read bf16 Abf_in (L3-resident after layer 1).
// grid: (N_ATOMS/64, KS), 256 threads = 4 waves; wave w owns 16 rows x 64 cols.
template <int CVT>
__global__ __launch_bounds__(256) void matmul_mfma_kernel(
        const float* __restrict__ A, const ushort_t* __restrict__ Abf_in,
        ushort_t* __restrict__ Abf_out, const ushort_t* __restrict__ hT,
        float* __restrict__ pbuf) {
    const int t  = threadIdx.x;
    const int w  = t >> 6;
    const int l  = t & 63;
    const int lm = l & 15;               // M-row (A frag) / N-col (B frag)
    const int lk = (l >> 4) << 3;        // k base within 32: 0,8,16,24
    const size_t row = (size_t)blockIdx.x * 64 + w * 16 + lm;
    const size_t kc0 = (size_t)blockIdx.y * KCH;
    const size_t abase = row * N_ATOMS + kc0 + lk;

    const ushort_t* bp0 = hT + (size_t)lm * N_ATOMS + kc0 + lk;
    const ushort_t* bp1 = bp0 + (size_t)16 * N_ATOMS;
    const ushort_t* bp2 = bp0 + (size_t)32 * N_ATOMS;
    const ushort_t* bp3 = bp0 + (size_t)48 * N_ATOMS;

    f32x4 acc0 = {0.f, 0.f, 0.f, 0.f};
    f32x4 acc1 = acc0, acc2 = acc0, acc3 = acc0;

#pragma unroll 4
    for (int kk = 0; kk < KCH; kk += 32) {
        short8v af;
        if (CVT) {
            float4 a0 = *(const float4*)(A + abase + kk);
            float4 a1 = *(const float4*)(A + abase + kk + 4);
            af[0] = (short)f2bf(a0.x); af[1] = (short)f2bf(a0.y);
            af[2] = (short)f2bf(a0.z); af[3] = (short)f2bf(a0.w);
            af[4] = (short)f2bf(a1.x); af[5] = (short)f2bf(a1.y);
            af[6] = (short)f2bf(a1.z); af[7] = (short)f2bf(a1.w);
            *(short8v*)(Abf_out + abase + kk) = af;
        } else {
            af = *(const short8v*)(Abf_in + abase + kk);
        }
        short8v b0 = *(const short8v*)(bp0 + kk);
        short8v b1 = *(const short8v*)(bp1 + kk);
        short8v b2 = *(const short8v*)(bp2 + kk);
        short8v b3 = *(const short8v*)(bp3 + kk);
        acc0 = __builtin_amdgcn_mfma_f32_16x16x32_bf16(af, b0, acc0, 0, 0, 0);
        acc1 = __builtin_amdgcn_mfma_f32_16x16x32_bf16(af, b1, acc1, 0, 0, 0);
        acc2 = __builtin_amdgcn_mfma_f32_16x16x32_bf16(af, b2, acc2, 0, 0, 0);
        acc3 = __builtin_amdgcn_mfma_f32_16x16x32_bf16(af, b3, acc3, 0, 0, 0);
    }

    // C/D layout: col = lane&15, row = (lane>>4)*4 + reg  [m89 verified]
    float* pb = pbuf + (size_t)blockIdx.y * (N_ATOMS * DIM);
    const int rbase = blockIdx.x * 64 + w * 16 + ((l >> 4) << 2);
#pragma unroll
    for (int j = 0; j < 4; ++j) {
        float* vp = pb + (size_t)(rbase + j) * DIM + lm;
        vp[0]  = acc0[j];
        vp[16] = acc1[j];
        vp[32] = acc2[j];
        vp[48] = acc3[j];
    }
}

// ---- vnext += sum over splits of pbuf (deterministic, no atomics) ----
__global__ __launch_bounds__(256) void reduce_kernel(
        const float* __restrict__ pbuf, float* __restrict__ vnext) {
    const size_t i = ((size_t)blockIdx.x * 256 + threadIdx.x) * 4;
    f32x4 s = *(const f32x4*)(vnext + i);
#pragma unroll
    for (int sp = 0; sp < KS; ++sp)
        s += *(const f32x4*)(pbuf + (size_t)sp * (N_ATOMS * DIM) + i);
    *(f32x4*)(vnext + i) = s;
}

// ------ segment sum ------
__device__ __forceinline__ int lower_bound_dev(const int* __restrict__ seg, int val) {
    int lo = 0, hi = N_ATOMS;
    while (lo < hi) {
        int mid = (lo + hi) >> 1;
        if (seg[mid] < val) lo = mid + 1; else hi = mid;
    }
    return lo;
}

__global__ void segsum_kernel(const float* __restrict__ v,
                              const int* __restrict__ seg,
                              float* __restrict__ out) {
    int m = blockIdx.x;
    int d = threadIdx.x;
    int lo = lower_bound_dev(seg, m);
    int hi = lower_bound_dev(seg, m + 1);
    float acc = 0.f;
    for (int n = lo; n < hi; ++n) acc += v[n * DIM + d];
    out[m * DIM + d] = acc;
}

extern "C" void kernel_launch(void* const* d_in, const int* in_sizes, int n_in,
                              void* d_out, int out_size, void* d_ws, size_t ws_size,
                              hipStream_t stream) {
    const int*   fp    = (const int*)d_in[0];
    const float* A     = (const float*)d_in[1];
    const int*   seg   = (const int*)d_in[2];
    const float* table = (const float*)d_in[3];
    const float* W     = (const float*)d_in[4];
    const float* b     = (const float*)d_in[5];
    float* out = (float*)d_out;

    float*    v0   = (float*)d_ws;                               // 2 MB
    float*    v1   = v0 + (size_t)N_ATOMS * DIM;                 // 2 MB
    float*    pbuf = v1 + (size_t)N_ATOMS * DIM;                 // 32 MB
    ushort_t* hT   = (ushort_t*)(pbuf + (size_t)KS * N_ATOMS * DIM);  // 1 MB
    ushort_t* Abf  = hT + (size_t)DIM * N_ATOMS;                 // 134 MB

    embed_kernel<<<N_ATOMS, DIM, 0, stream>>>(fp, table, v0);

    float* vcur = v0;
    float* vnext = v1;
    for (int l = 0; l < N_LAYERS; ++l) {
        linear_relu_T_kernel<<<N_ATOMS / 64, 256, 0, stream>>>(
            vcur, W + l * DIM * DIM, b + l * DIM, vnext, hT);
        dim3 grid(N_ATOMS / 64, KS);
        if (l == 0)
            matmul_mfma_kernel<1><<<grid, 256, 0, stream>>>(A, Abf, Abf, hT, pbuf);
        else
            matmul_mfma_kernel<0><<<grid, 256, 0, stream>>>(A, Abf, Abf, hT, pbuf);
        reduce_kernel<<<(N_ATOMS * DIM) / (256 * 4), 256, 0, stream>>>(pbuf, vnext);
        float* tmp = vcur; vcur = vnext; vnext = tmp;
    }

    segsum_kernel<<<N_MOL, DIM, 0, stream>>>(vcur, seg, out);
}

// Round 4
// 229.105 us; speedup vs baseline: 1.4820x; 1.4820x over previous
//
#include <hip/hip_runtime.h>

#define N_ATOMS 8192
#define DIM 64
#define N_MOL 256
#define N_LAYERS 3
#define KS 16
#define KCH (N_ATOMS / KS)   // 512 k per split
#define BM 128
#define BN 64
#define BK 64
#define NSTEP (KCH / BK)     // 8

typedef __attribute__((ext_vector_type(8))) short short8v;
typedef __attribute__((ext_vector_type(4))) float f32x4;
typedef unsigned short ushort_t;

// f32 -> bf16 RTNE (inputs finite)
__device__ __forceinline__ ushort_t f2bf(float x) {
    unsigned u = __float_as_uint(x);
    u += 0x7fffu + ((u >> 16) & 1u);
    return (ushort_t)(u >> 16);
}

// async global->LDS, 16B per lane, LDS dest = wave-uniform base + lane*16
__device__ __forceinline__ void gload16(const void* gsrc, void* ldst) {
    __builtin_amdgcn_global_load_lds(
        (const __attribute__((address_space(1))) void*)gsrc,
        (__attribute__((address_space(3))) void*)ldst, 16, 0, 0);
}

// ---------------- embed ----------------
__global__ void embed_kernel(const int* __restrict__ fp,
                             const float* __restrict__ table,
                             float* __restrict__ v) {
    int n = blockIdx.x;
    int d = threadIdx.x;
    v[n * DIM + d] = table[fp[n] * DIM + d];
}

// ---- linear+relu; writes vnext = h (f32 residual init) and hT (bf16 [DIM][N_ATOMS]) ----
__global__ __launch_bounds__(256) void linear_relu_T_kernel(
        const float* __restrict__ v, const float* __restrict__ W,
        const float* __restrict__ b, float* __restrict__ vnext,
        ushort_t* __restrict__ hT) {
    __shared__ float Ws[DIM][DIM + 1];
    __shared__ float vsT[DIM][68];

    const int t = threadIdx.x;
    const int n0 = blockIdx.x * 64;
    for (int i = t; i < DIM * DIM; i += 256) {
        Ws[i >> 6][i & 63] = W[i];
        float val = v[n0 * DIM + i];
        vsT[i & 63][i >> 6] = val;
    }
    __syncthreads();

    const int e = t & 63;
    const int g = t >> 6;
    float acc[16];
    const float be = b[e];
#pragma unroll
    for (int i = 0; i < 16; ++i) acc[i] = be;

    for (int d = 0; d < DIM; ++d) {
        const float w = Ws[e][d];
        const float4* vp = (const float4*)&vsT[d][g * 16];
        float4 x0 = vp[0], x1 = vp[1], x2 = vp[2], x3 = vp[3];
        acc[0]  += w * x0.x; acc[1]  += w * x0.y; acc[2]  += w * x0.z; acc[3]  += w * x0.w;
        acc[4]  += w * x1.x; acc[5]  += w * x1.y; acc[6]  += w * x1.z; acc[7]  += w * x1.w;
        acc[8]  += w * x2.x; acc[9]  += w * x2.y; acc[10] += w * x2.z; acc[11] += w * x2.w;
        acc[12] += w * x3.x; acc[13] += w * x3.y; acc[14] += w * x3.z; acc[15] += w * x3.w;
    }

    ushort_t hb[16];
#pragma unroll
    for (int i = 0; i < 16; ++i) {
        float hv = acc[i] > 0.f ? acc[i] : 0.f;
        const int n = n0 + g * 16 + i;
        vnext[(size_t)n * DIM + e] = hv;
        hb[i] = f2bf(hv);
    }
    ushort_t* hp = hT + (size_t)e * N_ATOMS + n0 + g * 16;
    *(short8v*)(hp)     = *(short8v*)&hb[0];
    *(short8v*)(hp + 8) = *(short8v*)&hb[8];
}

// ---- pbuf[split] = A[rows, ksplit] @ h  — LDS-staged, double-buffered, swizzled ----
// grid (N_ATOMS/BM, KS), 256 threads = 4 waves; wave w: rows w*32..+32, cols 0..64.
// LDS layout: tile[row][slot] with slot s (8 bf16 = 16B) stored at s ^ (row&7).
template <int CVT>
__global__ __launch_bounds__(256) void matmul_mfma_kernel(
        const float* __restrict__ A, const ushort_t* __restrict__ Abf_in,
        ushort_t* __restrict__ Abf_out, const ushort_t* __restrict__ hT,
        float* __restrict__ pbuf) {
    __shared__ ushort_t Asw[2][BM * BK];   // 2 x 16 KB
    __shared__ ushort_t Bsw[2][BN * BK];   // 2 x 8 KB

    const int t  = threadIdx.x;
    const int w  = t >> 6;
    const int l  = t & 63;
    const int lm = l & 15;
    const int lq = l >> 4;
    const int r0 = blockIdx.x * BM;
    const size_t kc0 = (size_t)blockIdx.y * KCH;

    auto stage = [&](int bi, size_t kb) {
        if (CVT) {
            // reg-staged: f32 loads (coalesced 32B/lane), cvt, swizzled ds_write + Abf store
#pragma unroll
            for (int q = 0; q < 4; ++q) {
                const int i = q * 256 + t;
                const int r = i >> 3, s = i & 7;
                const size_t goff = (size_t)(r0 + r) * N_ATOMS + kb + s * 8;
                const float4* g = (const float4*)(A + goff);
                float4 a0 = g[0], a1 = g[1];
                short8v vv;
                vv[0] = (short)f2bf(a0.x); vv[1] = (short)f2bf(a0.y);
                vv[2] = (short)f2bf(a0.z); vv[3] = (short)f2bf(a0.w);
                vv[4] = (short)f2bf(a1.x); vv[5] = (short)f2bf(a1.y);
                vv[6] = (short)f2bf(a1.z); vv[7] = (short)f2bf(a1.w);
                *(short8v*)&Asw[bi][r * BK + ((s ^ (r & 7)) << 3)] = vv;
                *(short8v*)(Abf_out + goff) = vv;
            }
        } else {
            // async gload_lds: linear LDS dest, inverse-swizzled global source (rule #21)
#pragma unroll
            for (int q = 0; q < 4; ++q) {
                const int i = q * 256 + t;
                const int r = i >> 3, s = i & 7;
                gload16(Abf_in + (size_t)(r0 + r) * N_ATOMS + kb + ((s ^ (r & 7)) << 3),
                        &Asw[bi][(q * 256 + w * 64) * 8]);
            }
        }
#pragma unroll
        for (int q = 0; q < 2; ++q) {
            const int i = q * 256 + t;
            const int r = i >> 3, s = i & 7;
            gload16(hT + (size_t)r * N_ATOMS + kb + ((s ^ (r & 7)) << 3),
                    &Bsw[bi][(q * 256 + w * 64) * 8]);
        }
    };

    f32x4 acc[2][4];
#pragma unroll
    for (int m = 0; m < 2; ++m)
#pragma unroll
        for (int n = 0; n < 4; ++n) acc[m][n] = (f32x4){0.f, 0.f, 0.f, 0.f};

    stage(0, kc0);
    __syncthreads();

    for (int ks = 0; ks < NSTEP; ++ks) {
        const int bi = ks & 1;
        if (ks + 1 < NSTEP) stage(bi ^ 1, kc0 + (size_t)(ks + 1) * BK);
#pragma unroll
        for (int kki = 0; kki < 2; ++kki) {
            // all fragment rows are == lm (mod 8) -> common swizzled slot offset
            const int sx = ((lq + kki * 4) ^ (lm & 7)) << 3;
            const int ra = w * 32 + lm;
            short8v a0 = *(const short8v*)&Asw[bi][ra * BK + sx];
            short8v a1 = *(const short8v*)&Asw[bi][(ra + 16) * BK + sx];
            short8v b0 = *(const short8v*)&Bsw[bi][(lm)      * BK + sx];
            short8v b1 = *(const short8v*)&Bsw[bi][(lm + 16) * BK + sx];
            short8v b2 = *(const short8v*)&Bsw[bi][(lm + 32) * BK + sx];
            short8v b3 = *(const short8v*)&Bsw[bi][(lm + 48) * BK + sx];
            acc[0][0] = __builtin_amdgcn_mfma_f32_16x16x32_bf16(a0, b0, acc[0][0], 0, 0, 0);
            acc[0][1] = __builtin_amdgcn_mfma_f32_16x16x32_bf16(a0, b1, acc[0][1], 0, 0, 0);
            acc[0][2] = __builtin_amdgcn_mfma_f32_16x16x32_bf16(a0, b2, acc[0][2], 0, 0, 0);
            acc[0][3] = __builtin_amdgcn_mfma_f32_16x16x32_bf16(a0, b3, acc[0][3], 0, 0, 0);
            acc[1][0] = __builtin_amdgcn_mfma_f32_16x16x32_bf16(a1, b0, acc[1][0], 0, 0, 0);
            acc[1][1] = __builtin_amdgcn_mfma_f32_16x16x32_bf16(a1, b1, acc[1][1], 0, 0, 0);
            acc[1][2] = __builtin_amdgcn_mfma_f32_16x16x32_bf16(a1, b2, acc[1][2], 0, 0, 0);
            acc[1][3] = __builtin_amdgcn_mfma_f32_16x16x32_bf16(a1, b3, acc[1][3], 0, 0, 0);
        }
        __syncthreads();   // drains gload_lds (vmcnt) + guards LDS buffer reuse
    }

    // C/D layout: col = lane&15, row = (lane>>4)*4 + reg  [m89 verified]
    float* pb = pbuf + (size_t)blockIdx.y * ((size_t)N_ATOMS * DIM);
    const int rb = r0 + w * 32 + lq * 4;
#pragma unroll
    for (int m = 0; m < 2; ++m)
#pragma unroll
        for (int j = 0; j < 4; ++j) {
            float* vp = pb + (size_t)(rb + m * 16 + j) * DIM + lm;
#pragma unroll
            for (int n = 0; n < 4; ++n) vp[n * 16] = acc[m][n][j];
        }
}

// ---- vnext += sum over splits of pbuf (deterministic) ----
__global__ __launch_bounds__(256) void reduce_kernel(
        const float* __restrict__ pbuf, float* __restrict__ vnext) {
    const size_t i = ((size_t)blockIdx.x * 256 + threadIdx.x) * 4;
    f32x4 s = *(const f32x4*)(vnext + i);
#pragma unroll
    for (int sp = 0; sp < KS; ++sp)
        s += *(const f32x4*)(pbuf + (size_t)sp * (N_ATOMS * DIM) + i);
    *(f32x4*)(vnext + i) = s;
}

// ------ segment sum ------
__device__ __forceinline__ int lower_bound_dev(const int* __restrict__ seg, int val) {
    int lo = 0, hi = N_ATOMS;
    while (lo < hi) {
        int mid = (lo + hi) >> 1;
        if (seg[mid] < val) lo = mid + 1; else hi = mid;
    }
    return lo;
}

__global__ void segsum_kernel(const float* __restrict__ v,
                              const int* __restrict__ seg,
                              float* __restrict__ out) {
    int m = blockIdx.x;
    int d = threadIdx.x;
    int lo = lower_bound_dev(seg, m);
    int hi = lower_bound_dev(seg, m + 1);
    float acc = 0.f;
    for (int n = lo; n < hi; ++n) acc += v[n * DIM + d];
    out[m * DIM + d] = acc;
}

extern "C" void kernel_launch(void* const* d_in, const int* in_sizes, int n_in,
                              void* d_out, int out_size, void* d_ws, size_t ws_size,
                              hipStream_t stream) {
    const int*   fp    = (const int*)d_in[0];
    const float* A     = (const float*)d_in[1];
    const int*   seg   = (const int*)d_in[2];
    const float* table = (const float*)d_in[3];
    const float* W     = (const float*)d_in[4];
    const float* b     = (const float*)d_in[5];
    float* out = (float*)d_out;

    float*    v0   = (float*)d_ws;
    float*    v1   = v0 + (size_t)N_ATOMS * DIM;
    float*    pbuf = v1 + (size_t)N_ATOMS * DIM;                      // KS*2MB = 32MB
    ushort_t* hT   = (ushort_t*)(pbuf + (size_t)KS * N_ATOMS * DIM);  // 1MB
    ushort_t* Abf  = hT + (size_t)DIM * N_ATOMS;                      // 134MB

    embed_kernel<<<N_ATOMS, DIM, 0, stream>>>(fp, table, v0);

    float* vcur = v0;
    float* vnext = v1;
    for (int l = 0; l < N_LAYERS; ++l) {
        linear_relu_T_kernel<<<N_ATOMS / 64, 256, 0, stream>>>(
            vcur, W + l * DIM * DIM, b + l * DIM, vnext, hT);
        dim3 grid(N_ATOMS / BM, KS);
        if (l == 0)
            matmul_mfma_kernel<1><<<grid, 256, 0, stream>>>(A, Abf, Abf, hT, pbuf);
        else
            matmul_mfma_kernel<0><<<grid, 256, 0, stream>>>(A, Abf, Abf, hT, pbuf);
        reduce_kernel<<<(N_ATOMS * DIM) / (256 * 4), 256, 0, stream>>>(pbuf, vnext);
        float* tmp = vcur; vcur = vnext; vnext = tmp;
    }

    segsum_kernel<<<N_MOL, DIM, 0, stream>>>(vcur, seg, out);
}

// Round 5
// 221.939 us; speedup vs baseline: 1.5299x; 1.0323x over previous
//
#include <hip/hip_runtime.h>

#define N_ATOMS 8192
#define DIM 64
#define N_MOL 256
#define N_LAYERS 3
#define KS 16
#define KCH (N_ATOMS / KS)   // 512 k per split
#define BM 128
#define BN 64
#define BK 64
#define NSTEP (KCH / BK)     // 8

typedef __attribute__((ext_vector_type(8))) short short8v;
typedef __attribute__((ext_vector_type(4))) float f32x4;
typedef unsigned short ushort_t;

// f32 -> bf16 RTNE (inputs finite)
__device__ __forceinline__ ushort_t f2bf(float x) {
    unsigned u = __float_as_uint(x);
    u += 0x7fffu + ((u >> 16) & 1u);
    return (ushort_t)(u >> 16);
}

// async global->LDS, 16B per lane, LDS dest = wave-uniform base + lane*16
__device__ __forceinline__ void gload16(const void* gsrc, void* ldst) {
    __builtin_amdgcn_global_load_lds(
        (const __attribute__((address_space(1))) void*)gsrc,
        (__attribute__((address_space(3))) void*)ldst, 16, 0, 0);
}

// ---- fused linear: v = (FIRST ? embed : h_prev + sum_sp pbuf); h = relu(W v + b)
// ---- writes h (f32) and hT (bf16 [DIM][N_ATOMS]). 32 atoms/block, 256 blocks.
template <int FIRST>
__global__ __launch_bounds__(256) void fused_linear_kernel(
        const int* __restrict__ fp, const float* __restrict__ table,
        const float* __restrict__ hprev, const float* __restrict__ pbuf,
        const float* __restrict__ W, const float* __restrict__ b,
        float* __restrict__ hout, ushort_t* __restrict__ hT) {
    __shared__ float Ws[DIM][DIM + 1];
    __shared__ float vsT[DIM][36];       // [d][n_local], 36 keeps 16B align

    const int t = threadIdx.x;
    const int n0 = blockIdx.x * 32;
    for (int i = t; i < DIM * DIM; i += 256) Ws[i >> 6][i & 63] = W[i];
    for (int i = t; i < 32 * DIM; i += 256) {
        const int nl = i >> 6, d = i & 63;
        const size_t n = n0 + nl;
        float val;
        if (FIRST) {
            val = table[(size_t)fp[n] * DIM + d];
        } else {
            val = hprev[n * DIM + d];
#pragma unroll
            for (int sp = 0; sp < KS; ++sp)
                val += pbuf[(size_t)sp * (N_ATOMS * DIM) + n * DIM + d];
        }
        vsT[d][nl] = val;
    }
    __syncthreads();

    const int e = t & 63;
    const int g = t >> 6;                // 4 groups x 8 atoms
    float acc[8];
    const float be = b[e];
#pragma unroll
    for (int i = 0; i < 8; ++i) acc[i] = be;

    for (int d = 0; d < DIM; ++d) {
        const float w = Ws[e][d];
        const float4* vp = (const float4*)&vsT[d][g * 8];
        float4 x0 = vp[0], x1 = vp[1];
        acc[0] += w * x0.x; acc[1] += w * x0.y; acc[2] += w * x0.z; acc[3] += w * x0.w;
        acc[4] += w * x1.x; acc[5] += w * x1.y; acc[6] += w * x1.z; acc[7] += w * x1.w;
    }

    ushort_t hb[8];
#pragma unroll
    for (int i = 0; i < 8; ++i) {
        float hv = acc[i] > 0.f ? acc[i] : 0.f;
        hout[(size_t)(n0 + g * 8 + i) * DIM + e] = hv;
        hb[i] = f2bf(hv);
    }
    *(short8v*)(hT + (size_t)e * N_ATOMS + n0 + g * 8) = *(short8v*)&hb[0];
}

// ---- pbuf[split] = A[rows, ksplit] @ h  — LDS-staged, double-buffered, swizzled ----
// grid (N_ATOMS/BM, KS), 256 threads = 4 waves; wave w: rows w*32..+32, cols 0..64.
// LDS layout: tile[row][slot], slot s (8 bf16 = 16B) stored at s ^ (row&7).
template <int CVT>
__global__ __launch_bounds__(256) void matmul_mfma_kernel(
        const float* __restrict__ A, const ushort_t* __restrict__ Abf_in,
        ushort_t* __restrict__ Abf_out, const ushort_t* __restrict__ hT,
        float* __restrict__ pbuf) {
    __shared__ ushort_t Asw[2][BM * BK];   // 2 x 16 KB
    __shared__ ushort_t Bsw[2][BN * BK];   // 2 x 8 KB

    const int t  = threadIdx.x;
    const int w  = t >> 6;
    const int l  = t & 63;
    const int lm = l & 15;
    const int lq = l >> 4;
    const int r0 = blockIdx.x * BM;
    const size_t kc0 = (size_t)blockIdx.y * KCH;

    auto stage = [&](int bi, size_t kb) {
        if (CVT) {
#pragma unroll
            for (int q = 0; q < 4; ++q) {
                const int i = q * 256 + t;
                const int r = i >> 3, s = i & 7;
                const size_t goff = (size_t)(r0 + r) * N_ATOMS + kb + s * 8;
                const float4* g = (const float4*)(A + goff);
                float4 a0 = g[0], a1 = g[1];
                short8v vv;
                vv[0] = (short)f2bf(a0.x); vv[1] = (short)f2bf(a0.y);
                vv[2] = (short)f2bf(a0.z); vv[3] = (short)f2bf(a0.w);
                vv[4] = (short)f2bf(a1.x); vv[5] = (short)f2bf(a1.y);
                vv[6] = (short)f2bf(a1.z); vv[7] = (short)f2bf(a1.w);
                *(short8v*)&Asw[bi][r * BK + ((s ^ (r & 7)) << 3)] = vv;
                *(short8v*)(Abf_out + goff) = vv;
            }
        } else {
#pragma unroll
            for (int q = 0; q < 4; ++q) {
                const int i = q * 256 + t;
                const int r = i >> 3, s = i & 7;
                gload16(Abf_in + (size_t)(r0 + r) * N_ATOMS + kb + ((s ^ (r & 7)) << 3),
                        &Asw[bi][(q * 256 + w * 64) * 8]);
            }
        }
#pragma unroll
        for (int q = 0; q < 2; ++q) {
            const int i = q * 256 + t;
            const int r = i >> 3, s = i & 7;
            gload16(hT + (size_t)r * N_ATOMS + kb + ((s ^ (r & 7)) << 3),
                    &Bsw[bi][(q * 256 + w * 64) * 8]);
        }
    };

    f32x4 acc[2][4];
#pragma unroll
    for (int m = 0; m < 2; ++m)
#pragma unroll
        for (int n = 0; n < 4; ++n) acc[m][n] = (f32x4){0.f, 0.f, 0.f, 0.f};

    stage(0, kc0);
    __syncthreads();

    for (int ks = 0; ks < NSTEP; ++ks) {
        const int bi = ks & 1;
        if (ks + 1 < NSTEP) stage(bi ^ 1, kc0 + (size_t)(ks + 1) * BK);
#pragma unroll
        for (int kki = 0; kki < 2; ++kki) {
            const int sx = ((lq + kki * 4) ^ (lm & 7)) << 3;
            const int ra = w * 32 + lm;
            short8v a0 = *(const short8v*)&Asw[bi][ra * BK + sx];
            short8v a1 = *(const short8v*)&Asw[bi][(ra + 16) * BK + sx];
            short8v b0 = *(const short8v*)&Bsw[bi][(lm)      * BK + sx];
            short8v b1 = *(const short8v*)&Bsw[bi][(lm + 16) * BK + sx];
            short8v b2 = *(const short8v*)&Bsw[bi][(lm + 32) * BK + sx];
            short8v b3 = *(const short8v*)&Bsw[bi][(lm + 48) * BK + sx];
            acc[0][0] = __builtin_amdgcn_mfma_f32_16x16x32_bf16(a0, b0, acc[0][0], 0, 0, 0);
            acc[0][1] = __builtin_amdgcn_mfma_f32_16x16x32_bf16(a0, b1, acc[0][1], 0, 0, 0);
            acc[0][2] = __builtin_amdgcn_mfma_f32_16x16x32_bf16(a0, b2, acc[0][2], 0, 0, 0);
            acc[0][3] = __builtin_amdgcn_mfma_f32_16x16x32_bf16(a0, b3, acc[0][3], 0, 0, 0);
            acc[1][0] = __builtin_amdgcn_mfma_f32_16x16x32_bf16(a1, b0, acc[1][0], 0, 0, 0);
            acc[1][1] = __builtin_amdgcn_mfma_f32_16x16x32_bf16(a1, b1, acc[1][1], 0, 0, 0);
            acc[1][2] = __builtin_amdgcn_mfma_f32_16x16x32_bf16(a1, b2, acc[1][2], 0, 0, 0);
            acc[1][3] = __builtin_amdgcn_mfma_f32_16x16x32_bf16(a1, b3, acc[1][3], 0, 0, 0);
        }
        __syncthreads();
    }

    float* pb = pbuf + (size_t)blockIdx.y * ((size_t)N_ATOMS * DIM);
    const int rb = r0 + w * 32 + lq * 4;
#pragma unroll
    for (int m = 0; m < 2; ++m)
#pragma unroll
        for (int j = 0; j < 4; ++j) {
            float* vp = pb + (size_t)(rb + m * 16 + j) * DIM + lm;
#pragma unroll
            for (int n = 0; n < 4; ++n) vp[n * 16] = acc[m][n][j];
        }
}

// ---- fused segsum: out[m][d] = sum_{n in seg m} (h[n][d] + sum_sp pbuf[sp][n][d]) ----
__device__ __forceinline__ int lower_bound_dev(const int* __restrict__ seg, int val) {
    int lo = 0, hi = N_ATOMS;
    while (lo < hi) {
        int mid = (lo + hi) >> 1;
        if (seg[mid] < val) lo = mid + 1; else hi = mid;
    }
    return lo;
}

__global__ __launch_bounds__(256) void fused_segsum_kernel(
        const float* __restrict__ h, const float* __restrict__ pbuf,
        const int* __restrict__ seg, float* __restrict__ out) {
    __shared__ float sm[4][DIM];
    const int m = blockIdx.x;
    const int d = threadIdx.x & 63;
    const int g = threadIdx.x >> 6;
    const int lo = lower_bound_dev(seg, m);
    const int hi = lower_bound_dev(seg, m + 1);
    float acc = 0.f;
    for (int n = lo + g; n < hi; n += 4) {
        float v = h[(size_t)n * DIM + d];
#pragma unroll
        for (int sp = 0; sp < KS; ++sp)
            v += pbuf[(size_t)sp * (N_ATOMS * DIM) + (size_t)n * DIM + d];
        acc += v;
    }
    sm[g][d] = acc;
    __syncthreads();
    if (g == 0) out[(size_t)m * DIM + d] = sm[0][d] + sm[1][d] + sm[2][d] + sm[3][d];
}

extern "C" void kernel_launch(void* const* d_in, const int* in_sizes, int n_in,
                              void* d_out, int out_size, void* d_ws, size_t ws_size,
                              hipStream_t stream) {
    const int*   fp    = (const int*)d_in[0];
    const float* A     = (const float*)d_in[1];
    const int*   seg   = (const int*)d_in[2];
    const float* table = (const float*)d_in[3];
    const float* W     = (const float*)d_in[4];
    const float* b     = (const float*)d_in[5];
    float* out = (float*)d_out;

    float*    h0   = (float*)d_ws;                                    // 2 MB
    float*    h1   = h0 + (size_t)N_ATOMS * DIM;                      // 2 MB
    float*    pbuf = h1 + (size_t)N_ATOMS * DIM;                      // 32 MB
    ushort_t* hT   = (ushort_t*)(pbuf + (size_t)KS * N_ATOMS * DIM);  // 1 MB
    ushort_t* Abf  = hT + (size_t)DIM * N_ATOMS;                      // 134 MB

    dim3 mmgrid(N_ATOMS / BM, KS);

    // layer 0
    fused_linear_kernel<1><<<N_ATOMS / 32, 256, 0, stream>>>(
        fp, table, nullptr, pbuf, W, b, h0, hT);
    matmul_mfma_kernel<1><<<mmgrid, 256, 0, stream>>>(A, Abf, Abf, hT, pbuf);
    // layer 1
    fused_linear_kernel<0><<<N_ATOMS / 32, 256, 0, stream>>>(
        fp, table, h0, pbuf, W + DIM * DIM, b + DIM, h1, hT);
    matmul_mfma_kernel<0><<<mmgrid, 256, 0, stream>>>(A, Abf, Abf, hT, pbuf);
    // layer 2
    fused_linear_kernel<0><<<N_ATOMS / 32, 256, 0, stream>>>(
        fp, table, h1, pbuf, W + 2 * DIM * DIM, b + 2 * DIM, h0, hT);
    matmul_mfma_kernel<0><<<mmgrid, 256, 0, stream>>>(A, Abf, Abf, hT, pbuf);
    // pooled output
    fused_segsum_kernel<<<N_MOL, 256, 0, stream>>>(h0, pbuf, seg, out);
}